// Round 1
// baseline (562.313 us; speedup 1.0000x reference)
//
#include <hip/hip_runtime.h>

// Shapes (fixed by the reference): N=4, T=8 -> NT=32 batches; C=C2=256; H*W=1024.
// scores[p,q] = sum_c K[c,p]*Q[c,q] / 16   (per batch), softmax over p (column-wise),
// p_val[c,q] = sum_p V[c,p]*attn[p,q].
// d_out = [ p_val : 32*256*1024 floats ][ attn : 32*1024*1024 floats ]

#define NT_BATCH 32
#define CDIM     256
#define HW       1024

using short8 = __attribute__((ext_vector_type(8))) short;  // 8 bf16 in 4 VGPRs
using f32x4  = __attribute__((ext_vector_type(4))) float;

__device__ __forceinline__ unsigned short f2bf(float f) {
  union { float f; unsigned u; } v; v.f = f;
  unsigned u = v.u;
  return (unsigned short)((u + 0x7FFFu + ((u >> 16) & 1u)) >> 16);  // RNE
}

// ---------------------------------------------------------------------------
// GEMM1: raw scaled scores -> attn region of d_out.
// A[m=p][k=c] = K[c][p] (transpose during staging), B[k=c][n=q] = Q[c][q].
// 128x128 tile per 256-thread block, 4 waves in 2x2, each wave 64x64 (4x4 MFMAs).
// ---------------------------------------------------------------------------
__global__ __launch_bounds__(256) void gemm1_scores(const float* __restrict__ K,
                                                    const float* __restrict__ Q,
                                                    float* __restrict__ S) {
  __shared__ __align__(16) unsigned short As[128][40];  // [p][c], stride 40: 2-way banks (free)
  __shared__ __align__(16) unsigned short Bs[128][40];  // [q][c]

  const int nt = blockIdx.y;
  const int pt = blockIdx.x >> 3, qt = blockIdx.x & 7;
  const int p0 = pt * 128, q0 = qt * 128;
  const float* Kb = K + (size_t)nt * (CDIM * HW);
  const float* Qb = Q + (size_t)nt * (CDIM * HW);
  float* Sb = S + (size_t)nt * (HW * HW);

  const int tid = threadIdx.x, lane = tid & 63, wave = tid >> 6;
  const int wm = wave >> 1, wn = wave & 1;
  const int ko = (lane >> 4) * 8;   // k offset of this lane's A/B fragment
  const int mrow = lane & 15;

  f32x4 zero = {0.f, 0.f, 0.f, 0.f};
  f32x4 acc[4][4];
  #pragma unroll
  for (int i = 0; i < 4; ++i)
    #pragma unroll
    for (int j = 0; j < 4; ++j) acc[i][j] = zero;

  for (int c0 = 0; c0 < CDIM; c0 += 32) {
    __syncthreads();
    #pragma unroll
    for (int it = 0; it < 4; ++it) {
      int idx = (it * 256 + tid) * 4;           // 0..4095
      int cc = idx >> 7, pp = idx & 127;        // 32 c-rows x 128 p-cols
      float4 kv = *(const float4*)&Kb[(size_t)(c0 + cc) * HW + p0 + pp];
      float4 qv = *(const float4*)&Qb[(size_t)(c0 + cc) * HW + q0 + pp];
      As[pp + 0][cc] = f2bf(kv.x); As[pp + 1][cc] = f2bf(kv.y);
      As[pp + 2][cc] = f2bf(kv.z); As[pp + 3][cc] = f2bf(kv.w);
      Bs[pp + 0][cc] = f2bf(qv.x); Bs[pp + 1][cc] = f2bf(qv.y);
      Bs[pp + 2][cc] = f2bf(qv.z); Bs[pp + 3][cc] = f2bf(qv.w);
    }
    __syncthreads();

    short8 a[4], b[4];
    #pragma unroll
    for (int i = 0; i < 4; ++i) {
      a[i] = *(const short8*)&As[wm * 64 + i * 16 + mrow][ko];
      b[i] = *(const short8*)&Bs[wn * 64 + i * 16 + mrow][ko];
    }
    #pragma unroll
    for (int i = 0; i < 4; ++i)
      #pragma unroll
      for (int j = 0; j < 4; ++j)
        acc[i][j] = __builtin_amdgcn_mfma_f32_16x16x32_bf16(a[i], b[j], acc[i][j], 0, 0, 0);
  }

  const int quad = lane >> 4;
  #pragma unroll
  for (int i = 0; i < 4; ++i) {
    int row0 = p0 + wm * 64 + i * 16 + quad * 4;
    #pragma unroll
    for (int j = 0; j < 4; ++j) {
      int col = q0 + wn * 64 + j * 16 + (lane & 15);
      #pragma unroll
      for (int r = 0; r < 4; ++r)
        Sb[(size_t)(row0 + r) * HW + col] = acc[i][j][r] * 0.0625f;
    }
  }
}

// ---------------------------------------------------------------------------
// In-place column softmax over p. One thread per column q; online (m,l) pass
// then normalize pass. Coalesced across threads (q contiguous).
// ---------------------------------------------------------------------------
__global__ __launch_bounds__(256) void softmax_col(float* __restrict__ S) {
  const int nt = blockIdx.y;
  const int q = blockIdx.x * 256 + threadIdx.x;
  float* col = S + (size_t)nt * (HW * HW) + q;

  float m = -1e30f, l = 0.f;
  for (int p = 0; p < HW; p += 8) {
    float s[8];
    #pragma unroll
    for (int k = 0; k < 8; ++k) s[k] = col[(size_t)(p + k) * HW];
    float mm = s[0];
    #pragma unroll
    for (int k = 1; k < 8; ++k) mm = fmaxf(mm, s[k]);
    float nm = fmaxf(m, mm);
    float add = 0.f;
    #pragma unroll
    for (int k = 0; k < 8; ++k) add += __expf(s[k] - nm);
    l = l * __expf(m - nm) + add;
    m = nm;
  }
  const float inv = 1.f / l;
  for (int p = 0; p < HW; p += 8) {
    float s[8];
    #pragma unroll
    for (int k = 0; k < 8; ++k) s[k] = col[(size_t)(p + k) * HW];
    #pragma unroll
    for (int k = 0; k < 8; ++k) col[(size_t)(p + k) * HW] = __expf(s[k] - m) * inv;
  }
}

// ---------------------------------------------------------------------------
// GEMM2: p_val[c,q] = sum_p V[c,p]*attn[p,q].
// A[m=c][k=p] = V (direct layout), B[k=p][n=q] = attn (transpose during staging,
// fp32 -> bf16 on the fly). Same tile structure as GEMM1; K-loop over p (32 chunks).
// ---------------------------------------------------------------------------
__global__ __launch_bounds__(256) void gemm2_pval(const float* __restrict__ V,
                                                  const float* __restrict__ A_,
                                                  float* __restrict__ O) {
  __shared__ __align__(16) unsigned short As[128][40];  // [c][p]
  __shared__ __align__(16) unsigned short Bs[128][40];  // [q][p]

  const int nt = blockIdx.y;
  const int ct = blockIdx.x >> 3, qt = blockIdx.x & 7;
  const int c0 = ct * 128, q0 = qt * 128;
  const float* Vb = V + (size_t)nt * (CDIM * HW);
  const float* Ab = A_ + (size_t)nt * (HW * HW);
  float* Ob = O + (size_t)nt * (CDIM * HW);

  const int tid = threadIdx.x, lane = tid & 63, wave = tid >> 6;
  const int wm = wave >> 1, wn = wave & 1;
  const int ko = (lane >> 4) * 8;
  const int mrow = lane & 15;

  f32x4 zero = {0.f, 0.f, 0.f, 0.f};
  f32x4 acc[4][4];
  #pragma unroll
  for (int i = 0; i < 4; ++i)
    #pragma unroll
    for (int j = 0; j < 4; ++j) acc[i][j] = zero;

  for (int ch = 0; ch < HW; ch += 32) {
    __syncthreads();
    #pragma unroll
    for (int it = 0; it < 4; ++it) {
      int idx = (it * 256 + tid) * 4;           // 0..4095
      {
        int cc = idx >> 5, pc = idx & 31;       // V tile: 128 c x 32 p
        float4 vv = *(const float4*)&Vb[(size_t)(c0 + cc) * HW + ch + pc];
        As[cc][pc + 0] = f2bf(vv.x); As[cc][pc + 1] = f2bf(vv.y);
        As[cc][pc + 2] = f2bf(vv.z); As[cc][pc + 3] = f2bf(vv.w);
      }
      {
        int pp = idx >> 7, qq = idx & 127;      // attn tile: 32 p x 128 q
        float4 av = *(const float4*)&Ab[(size_t)(ch + pp) * HW + q0 + qq];
        Bs[qq + 0][pp] = f2bf(av.x); Bs[qq + 1][pp] = f2bf(av.y);
        Bs[qq + 2][pp] = f2bf(av.z); Bs[qq + 3][pp] = f2bf(av.w);
      }
    }
    __syncthreads();

    short8 a[4], b[4];
    #pragma unroll
    for (int i = 0; i < 4; ++i) {
      a[i] = *(const short8*)&As[wm * 64 + i * 16 + mrow][ko];
      b[i] = *(const short8*)&Bs[wn * 64 + i * 16 + mrow][ko];
    }
    #pragma unroll
    for (int i = 0; i < 4; ++i)
      #pragma unroll
      for (int j = 0; j < 4; ++j)
        acc[i][j] = __builtin_amdgcn_mfma_f32_16x16x32_bf16(a[i], b[j], acc[i][j], 0, 0, 0);
  }

  const int quad = lane >> 4;
  #pragma unroll
  for (int i = 0; i < 4; ++i) {
    int row0 = c0 + wm * 64 + i * 16 + quad * 4;
    #pragma unroll
    for (int j = 0; j < 4; ++j) {
      int col = q0 + wn * 64 + j * 16 + (lane & 15);
      #pragma unroll
      for (int r = 0; r < 4; ++r)
        Ob[(size_t)(row0 + r) * HW + col] = acc[i][j][r];
    }
  }
}

// ---------------------------------------------------------------------------
extern "C" void kernel_launch(void* const* d_in, const int* in_sizes, int n_in,
                              void* d_out, int out_size, void* d_ws, size_t ws_size,
                              hipStream_t stream) {
  const float* key   = (const float*)d_in[0];
  const float* query = (const float*)d_in[1];
  const float* value = (const float*)d_in[2];
  float* out  = (float*)d_out;
  float* pval = out;                                    // 32*256*1024 floats
  float* attn = out + (size_t)NT_BATCH * CDIM * HW;     // 32*1024*1024 floats

  // 1) raw scaled scores into attn region
  gemm1_scores<<<dim3(64, NT_BATCH), 256, 0, stream>>>(key, query, attn);
  // 2) in-place column softmax
  softmax_col<<<dim3(4, NT_BATCH), 256, 0, stream>>>(attn);
  // 3) p_val = V @ attn
  gemm2_pval<<<dim3(16, NT_BATCH), 256, 0, stream>>>(value, attn, pval);
}

// Round 2
// 360.806 us; speedup vs baseline: 1.5585x; 1.5585x over previous
//
#include <hip/hip_runtime.h>
#include <hip/hip_bf16.h>

// N=4, T=8 -> NT=32 batches; C=C2=256; H*W=1024.
// e[p,q]    = exp(sum_c K[c,p]*Q[c,q] / 16)          (K1, raw, into attn region)
// colsum[q] = sum_p e[p,q]                            (K1, LDS reduce + global atomics)
// attn[p,q] = e[p,q]/colsum[q]  (K2, in-place normalize during staging)
// pval[c,q] = sum_p V[c,p]*attn[p,q]                  (K2, 32x32x16 bf16 MFMA)
// d_out = [ p_val : 32*256*1024 f32 ][ attn : 32*1024*1024 f32 ]

#define NT_BATCH 32
#define CDIM     256
#define HW       1024

using short8 = __attribute__((ext_vector_type(8))) short;   // 8 bf16 (4 VGPRs)
using f32x16 = __attribute__((ext_vector_type(16))) float;  // 32x32 MFMA acc
using f32x4v = __attribute__((ext_vector_type(4))) float;

__device__ __forceinline__ unsigned pk2(float a, float b) {
  float2 t; t.x = a; t.y = b;
  __hip_bfloat162 h = __float22bfloat162_rn(t);   // v_cvt_pk_bf16_f32
  return *reinterpret_cast<unsigned*>(&h);
}
__device__ __forceinline__ void wr64(void* dst, float a, float b, float c, float d) {
  uint2 v; v.x = pk2(a, b); v.y = pk2(c, d);
  *reinterpret_cast<uint2*>(dst) = v;
}
__device__ __forceinline__ void wr128(void* dst, f32x4v p0, f32x4v p1) {
  uint4 v; v.x = pk2(p0[0], p0[1]); v.y = pk2(p0[2], p0[3]);
  v.z = pk2(p1[0], p1[1]); v.w = pk2(p1[2], p1[3]);
  *reinterpret_cast<uint4*>(dst) = v;
}

// ---------------------------------------------------------------------------
// K1: scores -> exp -> raw e + column sums. 128x128 tile, BK=32, 4 waves.
// ---------------------------------------------------------------------------
__global__ __launch_bounds__(256) void k1_scores(const float* __restrict__ Kp,
                                                 const float* __restrict__ Qp,
                                                 float* __restrict__ E,
                                                 float* __restrict__ colsum) {
  __shared__ __align__(16) unsigned short As[128][40];  // [p][c]
  __shared__ __align__(16) unsigned short Bs[128][40];  // [q][c]
  __shared__ float csum[128];

  const int nt = blockIdx.y;
  const int pt = blockIdx.x >> 3, qt = blockIdx.x & 7;
  const int p0 = pt * 128, q0 = qt * 128;
  const float* Kb = Kp + (size_t)nt * (CDIM * HW);
  const float* Qb = Qp + (size_t)nt * (CDIM * HW);
  float* Eb = E + (size_t)nt * (HW * HW);

  const int t = threadIdx.x, lane = t & 63;
  const int wave = t >> 6, wm = wave >> 1, wn = wave & 1;
  const int l31 = lane & 31, lhi = lane >> 5;

  // swizzled staging map: bijective (pblk 0..31, cblk 0..7) over 256 threads,
  // chosen so simultaneous b64 writes spread over 16 bank-starts (2-way = free).
  const int pblk = ((t & 7) << 2) | ((t >> 3) & 3);
  const int cblk = ((t >> 5) + (t & 7)) & 7;
  const int sp = pblk << 2, sc = cblk << 2;

  if (t < 128) csum[t] = 0.f;

  f32x16 acc[2][2];
  #pragma unroll
  for (int m = 0; m < 2; ++m)
    #pragma unroll
    for (int n = 0; n < 2; ++n)
      #pragma unroll
      for (int r = 0; r < 16; ++r) acc[m][n][r] = 0.f;

  for (int c0 = 0; c0 < CDIM; c0 += 32) {
    f32x4v kv[4], qv[4];
    #pragma unroll
    for (int j = 0; j < 4; ++j) {
      kv[j] = *(const f32x4v*)&Kb[(size_t)(c0 + sc + j) * HW + p0 + sp];
      qv[j] = *(const f32x4v*)&Qb[(size_t)(c0 + sc + j) * HW + q0 + sp];
    }
    __syncthreads();  // previous iteration's fragment reads complete
    #pragma unroll
    for (int i = 0; i < 4; ++i) {
      wr64(&As[sp + i][sc], kv[0][i], kv[1][i], kv[2][i], kv[3][i]);
      wr64(&Bs[sp + i][sc], qv[0][i], qv[1][i], qv[2][i], qv[3][i]);
    }
    __syncthreads();
    #pragma unroll
    for (int ks = 0; ks < 2; ++ks) {
      short8 a[2], b[2];
      #pragma unroll
      for (int m = 0; m < 2; ++m)
        a[m] = *(const short8*)&As[wm * 64 + m * 32 + l31][ks * 16 + lhi * 8];
      #pragma unroll
      for (int n = 0; n < 2; ++n)
        b[n] = *(const short8*)&Bs[wn * 64 + n * 32 + l31][ks * 16 + lhi * 8];
      #pragma unroll
      for (int m = 0; m < 2; ++m)
        #pragma unroll
        for (int n = 0; n < 2; ++n)
          acc[m][n] = __builtin_amdgcn_mfma_f32_32x32x16_bf16(a[m], b[n], acc[m][n], 0, 0, 0);
    }
  }

  // epilogue: e = exp(s/16); write raw e; per-column partial sums
  float part[2] = {0.f, 0.f};
  #pragma unroll
  for (int m = 0; m < 2; ++m) {
    const int rbase = wm * 64 + m * 32 + (lhi << 2);
    #pragma unroll
    for (int n = 0; n < 2; ++n) {
      const int col = wn * 64 + n * 32 + l31;
      #pragma unroll
      for (int r = 0; r < 16; ++r) {
        int row = rbase + (r & 3) + ((r >> 2) << 3);
        float e = __expf(acc[m][n][r] * 0.0625f);
        Eb[(size_t)(p0 + row) * HW + q0 + col] = e;
        part[n] += e;
      }
    }
  }
  #pragma unroll
  for (int n = 0; n < 2; ++n)
    atomicAdd(&csum[wn * 64 + n * 32 + l31], part[n]);
  __syncthreads();
  if (t < 128) atomicAdd(&colsum[(size_t)nt * HW + q0 + t], csum[t]);
}

// ---------------------------------------------------------------------------
// K2: in-place attn normalize + pval GEMM. One block per (nt, 64-q strip):
// exclusive ownership makes the in-place read->scale->write race-free.
// ---------------------------------------------------------------------------
__global__ __launch_bounds__(256) void k2_pv(const float* __restrict__ Vp,
                                             float* __restrict__ E,
                                             const float* __restrict__ colsum,
                                             float* __restrict__ O) {
  __shared__ __align__(16) unsigned short Vs[256][72];  // [c][p]
  __shared__ __align__(16) unsigned short Ps[64][72];   // [q][p]
  __shared__ float inv_s[64];

  const int nt = blockIdx.y, qt = blockIdx.x;
  const int q0 = qt * 64;
  const float* Vb = Vp + (size_t)nt * (CDIM * HW);
  float* Eb = E + (size_t)nt * (HW * HW);
  float* Ob = O + (size_t)nt * (CDIM * HW);

  const int t = threadIdx.x, lane = t & 63, wave = t >> 6;
  const int l31 = lane & 31, lhi = lane >> 5;

  if (t < 64) inv_s[t] = 1.f / colsum[(size_t)nt * HW + q0 + t];

  // attn staging: micro 4p x 4q, bijective (qblk 0..15, pblk 0..15)
  const int qblk = ((t & 3) << 2) | ((t >> 2) & 3);
  const int pblk = ((t >> 4) + (t & 3)) & 15;
  const int sq = qblk << 2, sp = pblk << 2;
  // V staging: 4 c-rows x 16 p, coalesced 256B per 4 lanes
  const int vc = (t >> 2) << 2;
  const int vp = (t & 3) << 4;

  f32x16 acc[2][2];
  #pragma unroll
  for (int m = 0; m < 2; ++m)
    #pragma unroll
    for (int n = 0; n < 2; ++n)
      #pragma unroll
      for (int r = 0; r < 16; ++r) acc[m][n][r] = 0.f;

  __syncthreads();  // inv_s ready
  const f32x4v inv4 = *(const f32x4v*)&inv_s[sq];

  for (int pb = 0; pb < HW; pb += 64) {
    f32x4v ev[4];
    #pragma unroll
    for (int i = 0; i < 4; ++i)
      ev[i] = *(const f32x4v*)&Eb[(size_t)(pb + sp + i) * HW + q0 + sq];
    f32x4v vv[4][4];
    #pragma unroll
    for (int r = 0; r < 4; ++r)
      #pragma unroll
      for (int g = 0; g < 4; ++g)
        vv[r][g] = *(const f32x4v*)&Vb[(size_t)(vc + r) * HW + pb + vp + (g << 2)];

    // normalize; write attn back (exclusive per-thread ownership)
    #pragma unroll
    for (int i = 0; i < 4; ++i) {
      f32x4v a = ev[i] * inv4;
      *(f32x4v*)&Eb[(size_t)(pb + sp + i) * HW + q0 + sq] = a;
      ev[i] = a;
    }
    __syncthreads();  // previous iteration's fragment reads complete
    #pragma unroll
    for (int j = 0; j < 4; ++j)
      wr64(&Ps[sq + j][sp], ev[0][j], ev[1][j], ev[2][j], ev[3][j]);
    #pragma unroll
    for (int r = 0; r < 4; ++r) {
      wr128(&Vs[vc + r][vp], vv[r][0], vv[r][1]);
      wr128(&Vs[vc + r][vp + 8], vv[r][2], vv[r][3]);
    }
    __syncthreads();
    #pragma unroll
    for (int ks = 0; ks < 4; ++ks) {
      short8 a[2], b[2];
      #pragma unroll
      for (int m = 0; m < 2; ++m)
        a[m] = *(const short8*)&Vs[wave * 64 + m * 32 + l31][ks * 16 + lhi * 8];
      #pragma unroll
      for (int n = 0; n < 2; ++n)
        b[n] = *(const short8*)&Ps[n * 32 + l31][ks * 16 + lhi * 8];
      #pragma unroll
      for (int m = 0; m < 2; ++m)
        #pragma unroll
        for (int n = 0; n < 2; ++n)
          acc[m][n] = __builtin_amdgcn_mfma_f32_32x32x16_bf16(a[m], b[n], acc[m][n], 0, 0, 0);
    }
  }

  #pragma unroll
  for (int m = 0; m < 2; ++m) {
    const int cbase = wave * 64 + m * 32 + (lhi << 2);
    #pragma unroll
    for (int n = 0; n < 2; ++n) {
      const int col = q0 + n * 32 + l31;
      #pragma unroll
      for (int r = 0; r < 16; ++r) {
        int c = cbase + (r & 3) + ((r >> 2) << 3);
        Ob[(size_t)c * HW + col] = acc[m][n][r];
      }
    }
  }
}

// ---------------------------------------------------------------------------
extern "C" void kernel_launch(void* const* d_in, const int* in_sizes, int n_in,
                              void* d_out, int out_size, void* d_ws, size_t ws_size,
                              hipStream_t stream) {
  const float* key   = (const float*)d_in[0];
  const float* query = (const float*)d_in[1];
  const float* value = (const float*)d_in[2];
  float* out  = (float*)d_out;
  float* pval = out;
  float* attn = out + (size_t)NT_BATCH * CDIM * HW;
  float* colsum = (float*)d_ws;  // 32*1024 floats

  hipMemsetAsync(colsum, 0, (size_t)NT_BATCH * HW * sizeof(float), stream);
  k1_scores<<<dim3(64, NT_BATCH), 256, 0, stream>>>(key, query, attn, colsum);
  k2_pv<<<dim3(16, NT_BATCH), 256, 0, stream>>>(value, attn, colsum, pval);
}